// Round 5
// baseline (164.729 us; speedup 1.0000x reference)
//
#include <hip/hip_runtime.h>
#include <math.h>

#define WID 512
#define HEI 512
#define NB  16
#define HW  ((size_t)HEI * WID)
#define NEG_INF (-INFINITY)

typedef float f4 __attribute__((ext_vector_type(4)));

__device__ __forceinline__ float qmax4(f4 v) {
    return fmaxf(fmaxf(v.x, v.y), fmaxf(v.z, v.w));
}

// Horizontal 35-window max for 4 consecutive outputs (cols 4*c4..4*c4+3)
// from one row whose float j corresponds to image col (w0-20+j).
// Window for out col 4*c4+d = floats [4*c4+3+d, 4*c4+37+d] in f4 [c4, c4+10].
// (verified exact on HW in round 3, absmax=0.0)
__device__ __forceinline__ f4 hwin35(const f4* __restrict__ rp, int c4) {
    f4 vv[11];
    #pragma unroll
    for (int i = 0; i < 11; ++i) vv[i] = rp[c4 + i];
    float q[10];
    #pragma unroll
    for (int i = 1; i <= 9; ++i) q[i] = qmax4(vv[i]);
    float Q28 = fmaxf(fmaxf(fmaxf(q[2], q[3]), fmaxf(q[4], q[5])),
                      fmaxf(fmaxf(q[6], q[7]), q[8]));
    float Q18 = fmaxf(Q28, q[1]);
    float Q29 = fmaxf(Q28, q[9]);
    float s01 = fmaxf(vv[9].x, vv[9].y);
    float s23 = fmaxf(vv[1].z, vv[1].w);
    f4 o;
    o.x = fmaxf(fmaxf(Q18, vv[0].w), s01);
    o.y = fmaxf(Q18, fmaxf(s01, vv[9].z));
    o.z = fmaxf(fmaxf(Q29, vv[1].y), s23);
    o.w = fmaxf(Q29, fmaxf(s23, vv[10].x));
    return o;
}

// -------------------------------------------------------------------------
// Fully fused: channel-min + h-35max (in-place LDS) + v-35max + |r-t| +
// reduce + ticket finalize. grid (8,8,16); 256 thr; LDS 40.8 KB -> 3 blk/CU.
// cm[r][j] = channel-min at image (h0-17+r, w0-20+j), OOB = -inf.
// -------------------------------------------------------------------------
__global__ __launch_bounds__(256, 3) void ccp_fused_kernel(
    const float* __restrict__ rin, const float* __restrict__ tin,
    float* __restrict__ acc, float* __restrict__ out)
{
    __shared__ float cm[98][104];   // row stride 416 B (16B-aligned)
    __shared__ float red[4];

    const int tid = threadIdx.x;
    const int col = tid & 63;
    const int ty  = tid >> 6;       // wave id: output rows ty*16..ty*16+15
    const int w0  = blockIdx.x * 64;
    const int h0  = blockIdx.y * 64;
    const int b   = blockIdx.z;
    const int gb  = (w0 - 20) >> 2; // f4 image-col index of cm col 0 (exact /4)

    float rtv[16];
    float tsum = 0.0f;

    #pragma unroll
    for (int tensor = 0; tensor < 2; ++tensor) {
        const float* __restrict__ p =
            ((tensor == 0) ? rin : tin) + (size_t)b * 3 * HW;

        // ---- stage channel-min of region rows [h0-17,h0+80] x 26 f4 cols
        for (int i = tid; i < 3136; i += 256) {   // 98 rows x 32 lanes (26 used)
            int r = i >> 5, j = i & 31;
            if (j < 26) {
                int hh = h0 - 17 + r;
                int gc = gb + j;
                f4 v = {NEG_INF, NEG_INF, NEG_INF, NEG_INF};
                if (hh >= 0 && hh < HEI && gc >= 0 && gc < (WID >> 2)) {
                    const float* prow = p + (size_t)hh * WID;
                    f4 a0 = ((const f4*)prow)[gc];
                    f4 a1 = ((const f4*)(prow + HW))[gc];
                    f4 a2 = ((const f4*)(prow + 2 * HW))[gc];
                    v.x = fminf(fminf(a0.x, a1.x), a2.x);
                    v.y = fminf(fminf(a0.y, a1.y), a2.y);
                    v.z = fminf(fminf(a0.z, a1.z), a2.z);
                    v.w = fminf(fminf(a0.w, a1.w), a2.w);
                }
                *(f4*)&cm[r][4 * j] = v;
            }
        }
        __syncthreads();

        // ---- horizontal 35-max IN-PLACE: 1568 groups (98 rows x 16 f4).
        // Half A = rows 0..48 (g<784), half B = rows 49..97. computeB reads
        // only rows >=49 so it can overlap writeA (rows <=48, cols 0..63).
        f4 oA[4];
        #pragma unroll
        for (int k = 0; k < 4; ++k) {
            int g = tid + (k << 8);
            if (g < 784) oA[k] = hwin35((const f4*)&cm[g >> 4][0], g & 15);
        }
        __syncthreads();
        f4 oB[4];
        #pragma unroll
        for (int k = 0; k < 4; ++k) {
            int g = tid + (k << 8);
            if (g < 784) *(f4*)&cm[g >> 4][4 * (g & 15)] = oA[k];
            int g2 = g + 784;
            if (g2 < 1568) oB[k] = hwin35((const f4*)&cm[g2 >> 4][0], g2 & 15);
        }
        __syncthreads();
        #pragma unroll
        for (int k = 0; k < 4; ++k) {
            int g2 = tid + (k << 8) + 784;
            if (g2 < 1568) *(f4*)&cm[g2 >> 4][4 * (g2 & 15)] = oB[k];
        }
        __syncthreads();

        // ---- vertical 35-max from per-thread 50-row column (conflict-free:
        // one wave = one row per read, cols 0..63 stride-1)
        float vc[50];
        #pragma unroll
        for (int i = 0; i < 50; ++i) vc[i] = cm[ty * 16 + i][col];
        float q[12];
        #pragma unroll
        for (int i = 0; i < 12; ++i)
            q[i] = fmaxf(fmaxf(vc[4*i], vc[4*i+1]), fmaxf(vc[4*i+2], vc[4*i+3]));
        #pragma unroll
        for (int m = 0; m < 4; ++m) {
            float Qc = fmaxf(fmaxf(fmaxf(q[m+1], q[m+2]), fmaxf(q[m+3], q[m+4])),
                             fmaxf(fmaxf(q[m+5], q[m+6]), q[m+7]));
            float A  = fmaxf(Qc, q[m+8]);
            float o0 = fmaxf(fmaxf(Qc, q[m]),
                             fmaxf(fmaxf(vc[4*m+32], vc[4*m+33]), vc[4*m+34]));
            float o1 = fmaxf(A, fmaxf(fmaxf(vc[4*m+1], vc[4*m+2]), vc[4*m+3]));
            float o2 = fmaxf(A, fmaxf(fmaxf(vc[4*m+2], vc[4*m+3]), vc[4*m+36]));
            float o3 = fmaxf(A, fmaxf(fmaxf(vc[4*m+3], vc[4*m+36]), vc[4*m+37]));
            if (tensor == 0) {
                rtv[4*m] = o0; rtv[4*m+1] = o1; rtv[4*m+2] = o2; rtv[4*m+3] = o3;
            } else {
                tsum += fabsf(rtv[4*m]   - o0) + fabsf(rtv[4*m+1] - o1)
                      + fabsf(rtv[4*m+2] - o2) + fabsf(rtv[4*m+3] - o3);
            }
        }
        __syncthreads();   // protect cm before next tensor's staging
    }

    // ---- reduce: wave shuffle -> 4 partials -> atomic + ticket finalize
    #pragma unroll
    for (int off = 32; off > 0; off >>= 1)
        tsum += __shfl_down(tsum, off, 64);
    if (col == 0) red[ty] = tsum;
    __syncthreads();
    if (tid == 0) {
        float bs = red[0] + red[1] + red[2] + red[3];
        atomicAdd(acc, bs);
        __threadfence();
        unsigned tk = atomicAdd((unsigned*)(acc + 1), 1u);
        if (tk == 1023u) {                      // last of 1024 blocks
            float s = atomicAdd(acc, 0.0f);     // coherent final sum
            out[0] = 1.0f / (1.0f + expf(-s / 4194304.0f));
        }
    }
}

// -------------------------------------------------------------------------
extern "C" void kernel_launch(void* const* d_in, const int* in_sizes, int n_in,
                              void* d_out, int out_size, void* d_ws, size_t ws_size,
                              hipStream_t stream) {
    const float* rin = (const float*)d_in[0];   // restored [16,3,512,512]
    const float* tin = (const float*)d_in[1];   // target   [16,3,512,512]
    float* out = (float*)d_out;
    float* acc = (float*)d_ws;                  // [sum, ticket]

    hipMemsetAsync(acc, 0, 2 * sizeof(float), stream);

    dim3 g(WID / 64, HEI / 64, NB);
    hipLaunchKernelGGL(ccp_fused_kernel, g, dim3(256), 0, stream, rin, tin, acc, out);
}

// Round 7
// 144.328 us; speedup vs baseline: 1.1413x; 1.1413x over previous
//
#include <hip/hip_runtime.h>
#include <math.h>

#define WID 512
#define HEI 512
#define NB  16
#define HW  ((size_t)HEI * WID)
#define NEG_INF (-INFINITY)

typedef float f4 __attribute__((ext_vector_type(4)));

__device__ __forceinline__ float qmax4(f4 v) {
    return fmaxf(fmaxf(v.x, v.y), fmaxf(v.z, v.w));
}

// Horizontal 35-max: output cols 4*c4+d (d=0..3) from one sm row; reads f4
// [c4, c4+10] (sm float x = image col x-20; halo = -inf). HW-verified (R5,
// absmax=0.0).
__device__ __forceinline__ f4 hwin35(const f4* __restrict__ rp, int c4) {
    f4 vv[11];
    #pragma unroll
    for (int i = 0; i < 11; ++i) vv[i] = rp[c4 + i];
    float q[10];
    #pragma unroll
    for (int i = 1; i <= 9; ++i) q[i] = qmax4(vv[i]);
    float Q28 = fmaxf(fmaxf(fmaxf(q[2], q[3]), fmaxf(q[4], q[5])),
                      fmaxf(fmaxf(q[6], q[7]), q[8]));
    float Q18 = fmaxf(Q28, q[1]);
    float Q29 = fmaxf(Q28, q[9]);
    float s01 = fmaxf(vv[9].x, vv[9].y);
    float s23 = fmaxf(vv[1].z, vv[1].w);
    f4 o;
    o.x = fmaxf(fmaxf(Q18, vv[0].w), s01);
    o.y = fmaxf(Q18, fmaxf(s01, vv[9].z));
    o.z = fmaxf(fmaxf(Q29, vv[1].y), s23);
    o.w = fmaxf(Q29, fmaxf(s23, vv[10].x));
    return o;
}

// -------------------------------------------------------------------------
// Kernel A: channel-min + horizontal 35-max. 4 rows/block (one wave/row).
// Lane l handles image f4 l and l+64: ALL global & LDS accesses are
// consecutive-lane-consecutive-16B (full LDS throughput; no 32B-stride
// bank aliasing). NT loads: inputs read-once, keep L3 for intermediate.
// -------------------------------------------------------------------------
__global__ __launch_bounds__(256) void hmax_kernel(
    const float* __restrict__ rin, const float* __restrict__ tin,
    float* __restrict__ ws)
{
    __shared__ float sm[4][552];     // 20 halo + 512 + 20 halo floats
    const int tid = threadIdx.x;
    const int wv  = tid >> 6;        // wave = row within block
    const int l   = tid & 63;
    const int h   = blockIdx.x * 4 + wv;
    const int z   = blockIdx.y;      // tensor*16 + b
    const int b   = z & 15;
    const float* __restrict__ in = (z < NB) ? rin : tin;
    const float* __restrict__ p  = in + (size_t)b * 3 * HW + (size_t)h * WID;

    if (tid < 160) {                 // -inf halo for the block's 4 rows
        int r = tid / 40, j = tid % 40;
        sm[r][(j < 20) ? j : (j + 512)] = NEG_INF;
    }

    const f4* __restrict__ p0 = (const f4*)p;
    const f4* __restrict__ p1 = (const f4*)(p + HW);
    const f4* __restrict__ p2 = (const f4*)(p + 2 * HW);
    // image f4 j = l and l+64: two 1024B coalesced wave-loads per channel
    f4 a0 = __builtin_nontemporal_load(p0 + l);
    f4 b0 = __builtin_nontemporal_load(p1 + l);
    f4 c0 = __builtin_nontemporal_load(p2 + l);
    f4 a1 = __builtin_nontemporal_load(p0 + l + 64);
    f4 b1 = __builtin_nontemporal_load(p1 + l + 64);
    f4 c1 = __builtin_nontemporal_load(p2 + l + 64);
    f4 v0, v1;
    v0.x = fminf(fminf(a0.x, b0.x), c0.x);
    v0.y = fminf(fminf(a0.y, b0.y), c0.y);
    v0.z = fminf(fminf(a0.z, b0.z), c0.z);
    v0.w = fminf(fminf(a0.w, b0.w), c0.w);
    v1.x = fminf(fminf(a1.x, b1.x), c1.x);
    v1.y = fminf(fminf(a1.y, b1.y), c1.y);
    v1.z = fminf(fminf(a1.z, b1.z), c1.z);
    v1.w = fminf(fminf(a1.w, b1.w), c1.w);
    // sm float 20+4j is 16B-aligned (80+16j bytes); consecutive lanes -> +16B
    *(f4*)&sm[wv][20 + 4 * l]        = v0;
    *(f4*)&sm[wv][20 + 4 * (l + 64)] = v1;
    __syncthreads();

    // outputs: f4 l (cols 4l..4l+3) and f4 l+64; reads consecutive-lane
    const f4* __restrict__ smr = (const f4*)sm[wv];
    f4 o0 = hwin35(smr, l);
    f4 o1 = hwin35(smr, l + 64);
    f4* __restrict__ wp = (f4*)(ws + (size_t)z * HW + (size_t)h * WID);
    wp[l]      = o0;
    wp[l + 64] = o1;
}

// -------------------------------------------------------------------------
// Kernel B: vertical 35-max (both tensors) + |r-t| + reduce + ticket
// finalize. 128-tall x 64-wide tiles: halo 1.27x, LDS 41.5 KB -> 3 blk/CU.
// grid (8,4,16) = 512 blocks. Reads are L2/L3-hits (just-written data).
// vc column reads: lane l -> bank l%32, 2 addr/bank = conflict-free.
// Quad-max math HW-verified (R3/R5, absmax=0.0).
// -------------------------------------------------------------------------
__global__ __launch_bounds__(256, 3) void vmax_kernel(
    const float* __restrict__ ws, float* __restrict__ acc,
    float* __restrict__ out)
{
    __shared__ float cm2[162][64];   // region rows [h0-17, h0+144]
    __shared__ float red[4];
    const int tid = threadIdx.x;
    const int col = tid & 63;
    const int ty  = tid >> 6;        // wave: output rows ty*32 .. ty*32+31
    const int w0  = blockIdx.x * 64;
    const int h0  = blockIdx.y * 128;
    const int b   = blockIdx.z;

    float rtv[32];
    float tsum = 0.0f;

    #pragma unroll
    for (int tensor = 0; tensor < 2; ++tensor) {
        const float* __restrict__ pb = ws + (size_t)(tensor * NB + b) * HW;

        for (int i = tid; i < 2592; i += 256) {   // 162 rows x 16 f4
            int r = i >> 4, c4 = i & 15;
            int hh = h0 - 17 + r;
            f4 v = {NEG_INF, NEG_INF, NEG_INF, NEG_INF};
            if (hh >= 0 && hh < HEI)
                v = ((const f4*)pb)[hh * 128 + (w0 >> 2) + c4];
            *(f4*)&cm2[r][4 * c4] = v;
        }
        __syncthreads();

        #pragma unroll
        for (int g = 0; g < 2; ++g) {
            const int base = ty * 32 + g * 16;
            float vc[50];
            #pragma unroll
            for (int i = 0; i < 50; ++i) vc[i] = cm2[base + i][col];
            float q[12];
            #pragma unroll
            for (int i = 0; i < 12; ++i)
                q[i] = fmaxf(fmaxf(vc[4*i], vc[4*i+1]),
                             fmaxf(vc[4*i+2], vc[4*i+3]));
            #pragma unroll
            for (int m = 0; m < 4; ++m) {
                float Qc = fmaxf(fmaxf(fmaxf(q[m+1], q[m+2]), fmaxf(q[m+3], q[m+4])),
                                 fmaxf(fmaxf(q[m+5], q[m+6]), q[m+7]));
                float A  = fmaxf(Qc, q[m+8]);
                float o0 = fmaxf(fmaxf(Qc, q[m]),
                                 fmaxf(fmaxf(vc[4*m+32], vc[4*m+33]), vc[4*m+34]));
                float o1 = fmaxf(A, fmaxf(fmaxf(vc[4*m+1], vc[4*m+2]), vc[4*m+3]));
                float o2 = fmaxf(A, fmaxf(fmaxf(vc[4*m+2], vc[4*m+3]), vc[4*m+36]));
                float o3 = fmaxf(A, fmaxf(fmaxf(vc[4*m+3], vc[4*m+36]), vc[4*m+37]));
                const int k = g * 16 + 4 * m;
                if (tensor == 0) {
                    rtv[k] = o0; rtv[k+1] = o1; rtv[k+2] = o2; rtv[k+3] = o3;
                } else {
                    tsum += fabsf(rtv[k]   - o0) + fabsf(rtv[k+1] - o1)
                          + fabsf(rtv[k+2] - o2) + fabsf(rtv[k+3] - o3);
                }
            }
        }
        __syncthreads();   // protect cm2 before next tensor staging
    }

    // wave shuffle reduce -> 4 partials -> atomic + ticket finalize
    #pragma unroll
    for (int off = 32; off > 0; off >>= 1)
        tsum += __shfl_down(tsum, off, 64);
    if (col == 0) red[ty] = tsum;
    __syncthreads();
    if (tid == 0) {
        float bs = red[0] + red[1] + red[2] + red[3];
        atomicAdd(acc, bs);
        __threadfence();
        unsigned tk = atomicAdd((unsigned*)(acc + 1), 1u);
        if (tk == 511u) {                       // last of 512 blocks
            float s = atomicAdd(acc, 0.0f);     // coherent final sum
            out[0] = 1.0f / (1.0f + expf(-s / 4194304.0f));
        }
    }
}

// -------------------------------------------------------------------------
extern "C" void kernel_launch(void* const* d_in, const int* in_sizes, int n_in,
                              void* d_out, int out_size, void* d_ws, size_t ws_size,
                              hipStream_t stream) {
    const float* rin = (const float*)d_in[0];   // restored [16,3,512,512]
    const float* tin = (const float*)d_in[1];   // target   [16,3,512,512]
    float* out = (float*)d_out;

    float* wsf = (float*)d_ws;                  // [2][16][512][512] + acc
    float* acc = wsf + (size_t)2 * NB * HW;     // [sum, ticket]

    hipMemsetAsync(acc, 0, 2 * sizeof(float), stream);

    dim3 gA(HEI / 4, 2 * NB);
    hipLaunchKernelGGL(hmax_kernel, gA, dim3(256), 0, stream, rin, tin, wsf);

    dim3 gB(WID / 64, HEI / 128, NB);
    hipLaunchKernelGGL(vmax_kernel, gB, dim3(256), 0, stream, wsf, acc, out);
}